// Round 7
// baseline (292.351 us; speedup 1.0000x reference)
//
#include <hip/hip_runtime.h>
#include <hip/hip_bf16.h>

typedef __hip_bfloat16 bf16;
typedef __attribute__((ext_vector_type(8))) short short8;
typedef __attribute__((ext_vector_type(4))) float f32x4;

__device__ __forceinline__ float tofb(bf16 v) { return __bfloat162float(v); }
__device__ __forceinline__ bf16 tob(float v) { return __float2bfloat16(v); }
// bf16x2 packed in a uint: low 16 bits = element 2m, high = element 2m+1
__device__ __forceinline__ float lo_f(unsigned v) { return __uint_as_float(v << 16); }
__device__ __forceinline__ float hi_f(unsigned v) { return __uint_as_float(v & 0xffff0000u); }
__device__ __forceinline__ unsigned f2bf_bits(float f) {  // RNE f32->bf16 bits
    unsigned u = __float_as_uint(f);
    return (u + 0x7fffu + ((u >> 16) & 1u)) >> 16;
}

#define CHUNK 4096   // edges per block in packbin
#define REG   9216   // fixed binned region per bucket (mean 8192, 11 sigma slack)
#define PREG  13312  // padded csr region per bucket (REG + 4096 pad slack, pad-16)

// fragment-buffer offsets (shorts): [t][s][lane][j] layout, 512 shorts per (t,s)
#define W2_OFF   0        // 128x128: t8 s4 -> 16384
#define NA1_OFF  16384    // 128x16:  t1 s4 -> 2048
#define NA3_OFF  18432    // 128x16:  t1 s4 -> 2048
#define F1_OFF   20480    // 48x64:   t4 s2 -> 4096 (k>=48 zero-padded)
#define F2_OFF   24576    // 64x32:   t2 s2 -> 2048
#define FRAG_TOT 26624
#define FRAG_BLKS ((FRAG_TOT + 1023) / 1024)

// ---------------- merged pass A (1024 threads/block): blocks [0,EB) packbin edges
//                  (LDS-staged counting sort -> coalesced binned writes, 4 edges/thread);
//                  blocks [EB,EB+FRAG_BLKS) pack dense weights to MFMA B-fragments.
//                  bcur pre-zeroed by hipMemsetAsync (bucket-relative cursors).
//                  NO per-edge global atomics (round-4 lesson: 1.6M device atomics = +35 us).
__global__ __launch_bounds__(1024) void prep_kernel(
    const int* __restrict__ eidx, int* __restrict__ bcur,
    unsigned* __restrict__ binned, int E, int EB,
    const float* __restrict__ w2, const float* __restrict__ na1w,
    const float* __restrict__ na3w, const float* __restrict__ f1w,
    const float* __restrict__ f2w, unsigned short* __restrict__ wf) {
    int t = threadIdx.x;
    if (blockIdx.x >= EB) {   // ---- pack_frags part ----
        int idx = (blockIdx.x - EB) * 1024 + t;
        const float* src;
        int Kdim, Ndim, S, rel, off;
        if (idx < 16384)      { src = w2;   Kdim = 128; Ndim = 128; S = 4; rel = idx;          off = W2_OFF; }
        else if (idx < 18432) { src = na1w; Kdim = 128; Ndim = 16;  S = 4; rel = idx - 16384;  off = NA1_OFF; }
        else if (idx < 20480) { src = na3w; Kdim = 128; Ndim = 16;  S = 4; rel = idx - 18432;  off = NA3_OFF; }
        else if (idx < 24576) { src = f1w;  Kdim = 48;  Ndim = 64;  S = 2; rel = idx - 20480;  off = F1_OFF; }
        else if (idx < FRAG_TOT) { src = f2w; Kdim = 64; Ndim = 32; S = 2; rel = idx - 24576;  off = F2_OFF; }
        else return;
        int j = rel & 7;
        int lane = (rel >> 3) & 63;
        int s = (rel >> 9) % S;
        int tt = rel / (512 * S);
        int k = s * 32 + ((lane >> 4) << 3) + j;
        int nn = tt * 16 + (lane & 15);
        unsigned short v = 0;
        if (k < Kdim) v = (unsigned short)f2bf_bits(src[k * Ndim + nn]);
        wf[off + rel] = v;
        return;
    }
    // ---- packbin part: LDS counting sort, then coalesced run writes ----
    __shared__ int h[256];
    __shared__ int lofs[256];
    __shared__ int lcur[256];
    __shared__ int gbase[256];
    __shared__ unsigned sorted[CHUNK];   // 16 KB
    __shared__ int sodd;
    if (t < 256) { h[t] = 0; lcur[t] = 0; }
    if (t == 0) sodd = 0;
    __syncthreads();
    if (t < 32) atomicOr(&sodd, eidx[2 * t + 1]);
    __syncthreads();
    int stride = (sodd == 0) ? 2 : 1;   // raw int64 => stride 2
    int base = blockIdx.x * CHUNK;
    int cnt = E - base; if (cnt > CHUNK) cnt = CHUNK;
    unsigned v[CHUNK / 1024];
#pragma unroll
    for (int k = 0; k < CHUNK / 1024; ++k) {
        int e = base + k * 1024 + t;
        if (e < E) {
            unsigned s = (unsigned)eidx[(size_t)e * stride];
            unsigned d = (unsigned)eidx[(size_t)E * stride + (size_t)e * stride];
            v[k] = (s << 16) | d;
            atomicAdd(&h[d >> 8], 1);
        } else {
            v[k] = 0xffffffffu;   // unused
        }
    }
    __syncthreads();
    int mycnt = (t < 256) ? h[t] : 0;
    if (t < 256) {
        if (mycnt) gbase[t] = t * REG + atomicAdd(&bcur[t], mycnt);  // bcur bucket-relative
        lofs[t] = mycnt;
    }
    __syncthreads();
    for (int off = 1; off < 256; off <<= 1) {            // inclusive scan of counts
        int x = (t >= off && t < 256) ? lofs[t - off] : 0;
        __syncthreads();
        if (t < 256) lofs[t] += x;
        __syncthreads();
    }
    int excl = (t < 256) ? (lofs[t] - mycnt) : 0;
    __syncthreads();
    if (t < 256) lofs[t] = excl;                         // exclusive offsets
    __syncthreads();
#pragma unroll
    for (int k = 0; k < CHUNK / 1024; ++k) {             // scatter into LDS (cheap atomics)
        int e = base + k * 1024 + t;
        if (e < E) {
            int b = (v[k] >> 8) & 255;
            int p = lofs[b] + atomicAdd(&lcur[b], 1);
            sorted[p] = v[k];
        }
    }
    __syncthreads();
    for (int j = t; j < cnt; j += 1024) {                // coalesced run writes to binned
        unsigned w = sorted[j];
        int b = (w >> 8) & 255;
        binned[gbase[b] + (j - lofs[b])] = w;
    }
}

// ---------------- pass B: per-bucket counting sort; FULL padded CSR image built in LDS,
//                  then one coalesced linear copy to global. 1024 threads/block. ----
__global__ __launch_bounds__(1024) void sort_kernel(const unsigned* __restrict__ binned,
                                                    const int* __restrict__ bcur,
                                                    int* __restrict__ offs,
                                                    int* __restrict__ pend,
                                                    float* __restrict__ dinv,
                                                    int* __restrict__ csr, int n, int zrow) {
    __shared__ int lcnt[256];
    __shared__ int lscan[256];
    __shared__ int lpos[256];
    __shared__ int sortedL[PREG];   // 53 KB padded CSR image
    int b = blockIdx.x, t = threadIdx.x;
    int bstart = b * REG;
    int bsize = bcur[b];            // bucket-relative count
    int pbase = b * PREG;
    if (t < 256) lcnt[t] = 0;
    __syncthreads();
    for (int e = t; e < bsize; e += 1024)
        atomicAdd(&lcnt[binned[bstart + e] & 255u], 1);
    __syncthreads();
    int node = (b << 8) + (t & 255);
    int myc = 0, mypad = 0;
    if (t < 256) {
        myc = lcnt[t];
        mypad = (node < n) ? ((myc + 1 + 15) & ~15) : 0;   // self + pad to multiple of 16
        lscan[t] = mypad;
    }
    __syncthreads();
    for (int off = 1; off < 256; off <<= 1) {
        int x = (t >= off && t < 256) ? lscan[t - off] : 0;
        __syncthreads();
        if (t < 256) lscan[t] += x;
        __syncthreads();
    }
    int totpad = lscan[255];
    if (t < 256) {
        int pexcl = lscan[t] - mypad;
        if (node < n) {
            offs[node] = pbase + pexcl;
            pend[node] = pbase + pexcl + mypad;
            dinv[node] = rsqrtf((float)myc + 1.0f);  // +1 self-loop
            sortedL[pexcl] = node;                   // self-loop entry
            for (int q = myc + 1; q < mypad; ++q) sortedL[pexcl + q] = zrow;
        }
        lpos[t] = pexcl + 1;                         // sources start after self
    }
    __syncthreads();
    for (int e = t; e < bsize; e += 1024) {
        unsigned v = binned[bstart + e];
        int p = atomicAdd(&lpos[v & 255u], 1);
        sortedL[p] = (int)(v >> 16);
    }
    __syncthreads();
    for (int j = t; j < totpad; j += 1024)           // fully coalesced CSR write
        csr[pbase + j] = sortedL[j];
}

// ---------------- pre-pass (16 nodes/block): hsx = dinv*x (bf16, 16-dim); gg; zero-rows ------
// Layer-1 commute: x1 = relu(dinv_i*(sum_j dinv_j x_j)@W1 + b1), so the gather table is the
// 16-dim dinv-scaled x (32 B/row, 1.6 MB total -> L2-resident) instead of 128-dim x@W1.

__global__ __launch_bounds__(256) void pre_kernel(
    const float* __restrict__ x,
    const float* __restrict__ ln1_w, const float* __restrict__ ln1_b,
    const float* __restrict__ ln2_w, const float* __restrict__ ln2_b,
    const float* __restrict__ dinv,
    bf16* __restrict__ hsx, bf16* __restrict__ hs2, bf16* __restrict__ gg, int n) {
    int tid = threadIdx.x;
    int i0 = blockIdx.x * 16;
    __shared__ float xls[16 * 20];   // [node][16] pad 20
    __shared__ float tg[16 * 36];    // ln1 out [node][32] pad 36
    if (blockIdx.x == 0) {           // zero rows (index n) for padded gathers
        if (tid < 16)  hsx[(size_t)n * 16 + tid] = tob(0.f);
        if (tid < 128) hs2[(size_t)n * 128 + tid] = tob(0.f);
    }
    {
        int nn = tid >> 4, cc = tid & 15;
        int i = i0 + nn;
        float xv = (i < n) ? x[(size_t)i * 16 + cc] : 0.f;
        xls[nn * 20 + cc] = xv;
        if (i < n) hsx[(size_t)i * 16 + cc] = tob(dinv[i] * xv);
    }
    __syncthreads();
    {
        int c = tid & 31, q = tid >> 5;
        float t0 = ln1_b[c], t1 = t0;
#pragma unroll
        for (int k = 0; k < 16; ++k) {
            float w = ln1_w[k * 32 + c];
            t0 += xls[q * 20 + k] * w;
            t1 += xls[(q + 8) * 20 + k] * w;
        }
        tg[q * 36 + c] = fmaxf(t0, 0.f);
        tg[(q + 8) * 36 + c] = fmaxf(t1, 0.f);
    }
    __syncthreads();
    {
        int nn = tid >> 4, cc = tid & 15;
        float t = ln2_b[cc];
#pragma unroll 8
        for (int k = 0; k < 32; ++k) t += tg[nn * 36 + k] * ln2_w[k * 16 + cc];
        int i = i0 + nn;
        if (i < n) gg[(size_t)i * 16 + cc] = tob(fmaxf(t, 0.f));
    }
}

#define ACC8(v)                              \
    a0 += lo_f((v).x); a1 += hi_f((v).x);    \
    a2 += lo_f((v).y); a3 += hi_f((v).y);    \
    a4 += lo_f((v).z); a5 += hi_f((v).z);    \
    a6 += lo_f((v).w); a7 += hi_f((v).w);

#define RED8(m)                                                  \
    a0 += __shfl_xor(a0, m); a1 += __shfl_xor(a1, m);            \
    a2 += __shfl_xor(a2, m); a3 += __shfl_xor(a3, m);            \
    a4 += __shfl_xor(a4, m); a5 += __shfl_xor(a5, m);            \
    a6 += __shfl_xor(a6, m); a7 += __shfl_xor(a7, m);

// 8-deep hand-pipelined gather (round-7): VGPR=32 at the old rolled-4 structure proved only
// ~4 loads in flight; the kernel is outstanding-miss bound (563 MB would take 16 us at L2 BW,
// measured 52 us). Issue 8 loads, then interleave consume/issue for the next 8. Peak live
// buffers ~8 uint4 -> ~60 VGPR, still in the 8-waves/SIMD band. csr prefetch retained.
// group g (16 lanes) owns node i; lane sl covers cols sl*8..+7.
#define GATHER16(hs, ...)                                                            \
    {                                                                                \
        const char* base = (const char*)(hs);                                        \
        int off16 = sl * 16;                                                         \
        float a0 = 0.f, a1 = 0.f, a2 = 0.f, a3 = 0.f,                                \
              a4 = 0.f, a5 = 0.f, a6 = 0.f, a7 = 0.f;                                \
        int e0 = 0, e1 = 0;                                                          \
        if (valid) { e0 = offs[i]; e1 = pend[i]; }                                   \
        int idxv = (e0 < e1) ? csr[e0 + sl] : 0;                                     \
        for (int cb = e0; cb < e1; cb += 16) {                                       \
            int idxn = csr[cb + 16 + sl];                                            \
            int s0 = __shfl(idxv, glane + 0);                                        \
            int s1 = __shfl(idxv, glane + 1);                                        \
            int s2 = __shfl(idxv, glane + 2);                                        \
            int s3 = __shfl(idxv, glane + 3);                                        \
            int s4 = __shfl(idxv, glane + 4);                                        \
            int s5 = __shfl(idxv, glane + 5);                                        \
            int s6 = __shfl(idxv, glane + 6);                                        \
            int s7 = __shfl(idxv, glane + 7);                                        \
            uint4 v0 = *(const uint4*)(base + (size_t)s0 * 256 + off16);             \
            uint4 v1 = *(const uint4*)(base + (size_t)s1 * 256 + off16);             \
            uint4 v2 = *(const uint4*)(base + (size_t)s2 * 256 + off16);             \
            uint4 v3 = *(const uint4*)(base + (size_t)s3 * 256 + off16);             \
            uint4 v4 = *(const uint4*)(base + (size_t)s4 * 256 + off16);             \
            uint4 v5 = *(const uint4*)(base + (size_t)s5 * 256 + off16);             \
            uint4 v6 = *(const uint4*)(base + (size_t)s6 * 256 + off16);             \
            uint4 v7 = *(const uint4*)(base + (size_t)s7 * 256 + off16);             \
            int s8  = __shfl(idxv, glane + 8);                                       \
            int s9  = __shfl(idxv, glane + 9);                                       \
            int s10 = __shfl(idxv, glane + 10);                                      \
            int s11 = __shfl(idxv, glane + 11);                                      \
            int s12 = __shfl(idxv, glane + 12);                                      \
            int s13 = __shfl(idxv, glane + 13);                                      \
            int s14 = __shfl(idxv, glane + 14);                                      \
            int s15 = __shfl(idxv, glane + 15);                                      \
            ACC8(v0)                                                                 \
            uint4 w0 = *(const uint4*)(base + (size_t)s8 * 256 + off16);             \
            ACC8(v1)                                                                 \
            uint4 w1 = *(const uint4*)(base + (size_t)s9 * 256 + off16);             \
            ACC8(v2)                                                                 \
            uint4 w2 = *(const uint4*)(base + (size_t)s10 * 256 + off16);            \
            ACC8(v3)                                                                 \
            uint4 w3 = *(const uint4*)(base + (size_t)s11 * 256 + off16);            \
            ACC8(v4)                                                                 \
            uint4 w4 = *(const uint4*)(base + (size_t)s12 * 256 + off16);            \
            ACC8(v5)                                                                 \
            uint4 w5 = *(const uint4*)(base + (size_t)s13 * 256 + off16);            \
            ACC8(v6)                                                                 \
            uint4 w6 = *(const uint4*)(base + (size_t)s14 * 256 + off16);            \
            ACC8(v7)                                                                 \
            uint4 w7 = *(const uint4*)(base + (size_t)s15 * 256 + off16);            \
            ACC8(w0) ACC8(w1) ACC8(w2) ACC8(w3)                                      \
            ACC8(w4) ACC8(w5) ACC8(w6) ACC8(w7)                                      \
            idxv = idxn;                                                             \
        }                                                                            \
        __VA_ARGS__                                                                  \
    }

// epilogue: relu(dinv*acc + bias) -> bf16 row in LDS xsb (stride 272 B)
#define STORE_X_BF16(biasptr)                                                        \
    {                                                                                \
        float r0 = 0.f; float r1 = 0.f; float r2 = 0.f; float r3 = 0.f;              \
        float r4 = 0.f; float r5 = 0.f; float r6 = 0.f; float r7 = 0.f;              \
        if (valid) {                                                                 \
            float di = dinv[i];                                                      \
            const float* b = (biasptr) + sl * 8;                                     \
            r0 = fmaxf(di * a0 + b[0], 0.f); r1 = fmaxf(di * a1 + b[1], 0.f);        \
            r2 = fmaxf(di * a2 + b[2], 0.f); r3 = fmaxf(di * a3 + b[3], 0.f);        \
            r4 = fmaxf(di * a4 + b[4], 0.f); r5 = fmaxf(di * a5 + b[5], 0.f);        \
            r6 = fmaxf(di * a6 + b[6], 0.f); r7 = fmaxf(di * a7 + b[7], 0.f);        \
        }                                                                            \
        uint4 pk;                                                                    \
        pk.x = f2bf_bits(r0) | (f2bf_bits(r1) << 16);                                \
        pk.y = f2bf_bits(r2) | (f2bf_bits(r3) << 16);                                \
        pk.z = f2bf_bits(r4) | (f2bf_bits(r5) << 16);                                \
        pk.w = f2bf_bits(r6) | (f2bf_bits(r7) << 16);                                \
        *(uint4*)((char*)xsb + g * 272 + sl * 16) = pk;                              \
    }

// ---------------- agg1 fused: gather 16-dim hsx -> aggx; x1 = relu(aggx@W1+b1) (VALU);
//                  hs2=dinv*(x1@W2) MFMA; a1 branch MFMA ----

__global__ __launch_bounds__(256) void agg1_kernel(
    const bf16* __restrict__ hsx, const int* __restrict__ offs, const int* __restrict__ pend,
    const int* __restrict__ csr,
    const float* __restrict__ dinv,
    const float* __restrict__ conv1_w, const float* __restrict__ conv1_b,
    const unsigned short* __restrict__ wfrag,
    const float* __restrict__ na1_b,
    const float* __restrict__ na2_w, const float* __restrict__ na2_b,
    bf16* __restrict__ hs2, bf16* __restrict__ a1, int n) {
    int tid = threadIdx.x;
    int g = tid >> 4, sl = tid & 15;
    int glane = tid & 48;
    int i0 = blockIdx.x * 16;
    int i = i0 + g;
    bool valid = (i < n);
    __shared__ float aggx[16 * 20];   // aggregated dinv-scaled x, [node][16] f32 pad 20
    __shared__ short xsb[16 * 136];   // x1 bf16, row stride 272 B
    __shared__ float pna[4 * 256];    // na1 per-wave partials
    __shared__ float t1s[16 * 20];
    // gather: 32-B rows, 2 lanes per row (col-halves), 16 rows per CSR chunk, csr prefetch
    {
        const char* base = (const char*)hsx;
        int off16 = (sl & 1) * 16;
        int rsel = glane + (sl >> 1);
        float a0 = 0.f, a1 = 0.f, a2 = 0.f, a3 = 0.f,
              a4 = 0.f, a5 = 0.f, a6 = 0.f, a7 = 0.f;   // local a1 shadows param (scope-limited)
        int e0 = 0, e1 = 0;
        if (valid) { e0 = offs[i]; e1 = pend[i]; }
        int idxv = (e0 < e1) ? csr[e0 + sl] : 0;
        for (int cb = e0; cb < e1; cb += 16) {
            int idxn = csr[cb + 16 + sl];   // safe: PREG slack + tail
            int s0 = __shfl(idxv, rsel);
            int s1 = __shfl(idxv, rsel + 8);
            uint4 v0 = *(const uint4*)(base + (size_t)s0 * 32 + off16);
            uint4 v1 = *(const uint4*)(base + (size_t)s1 * 32 + off16);
            ACC8(v0) ACC8(v1)
            idxv = idxn;
        }
        RED8(2) RED8(4) RED8(8)
        if (sl < 2) {
            float di = valid ? dinv[i] : 0.f;
            float4 p0 = {di * a0, di * a1, di * a2, di * a3};
            float4 p1 = {di * a4, di * a5, di * a6, di * a7};
            *(float4*)(aggx + g * 20 + sl * 8) = p0;
            *(float4*)(aggx + g * 20 + sl * 8 + 4) = p1;
        }
    }
    __syncthreads();
    // x1 = relu(aggx @ W1 + b1) -> bf16 rows in xsb (VALU, 16x128x16 per block)
    {
        int c = tid & 127, half = tid >> 7;
        float h[8];
#pragma unroll
        for (int r = 0; r < 8; ++r) h[r] = 0.f;
#pragma unroll
        for (int k = 0; k < 16; ++k) {
            float w = conv1_w[k * 128 + c];
#pragma unroll
            for (int r = 0; r < 8; ++r) h[r] += aggx[(half + 2 * r) * 20 + k] * w;
        }
        float bia = conv1_b[c];
#pragma unroll
        for (int r = 0; r < 8; ++r) {
            int nd = half + 2 * r;
            float v = fmaxf(h[r] + bia, 0.f);
            if (i0 + nd >= n) v = 0.f;
            xsb[nd * 136 + c] = (short)f2bf_bits(v);
        }
    }
    __syncthreads();
    int lane = tid & 63, wv = tid >> 6, quad = lane >> 4, lm = lane & 15;
    // conv2 via MFMA: wave wv covers col-tiles 2wv, 2wv+1
    {
        int t0 = wv * 2;
        f32x4 acc0 = {0.f, 0.f, 0.f, 0.f};
        f32x4 acc1 = {0.f, 0.f, 0.f, 0.f};
#pragma unroll
        for (int s = 0; s < 4; ++s) {
            short8 a = *(const short8*)((const char*)xsb + lm * 272 + s * 64 + quad * 16);
            short8 b0 = *(const short8*)(wfrag + W2_OFF + ((t0 * 4 + s) * 64 + lane) * 8);
            short8 b1 = *(const short8*)(wfrag + W2_OFF + (((t0 + 1) * 4 + s) * 64 + lane) * 8);
            acc0 = __builtin_amdgcn_mfma_f32_16x16x32_bf16(a, b0, acc0, 0, 0, 0);
            acc1 = __builtin_amdgcn_mfma_f32_16x16x32_bf16(a, b1, acc1, 0, 0, 0);
        }
#pragma unroll
        for (int r = 0; r < 4; ++r) {
            int iN = i0 + quad * 4 + r;
            if (iN < n) {
                float di = dinv[iN];
                hs2[(size_t)iN * 128 + t0 * 16 + lm] = tob(di * acc0[r]);
                hs2[(size_t)iN * 128 + (t0 + 1) * 16 + lm] = tob(di * acc1[r]);
            }
        }
    }
    // na1 via MFMA: wave wv computes K-step s=wv partial
    {
        f32x4 acc = {0.f, 0.f, 0.f, 0.f};
        short8 a = *(const short8*)((const char*)xsb + lm * 272 + wv * 64 + quad * 16);
        short8 b = *(const short8*)(wfrag + NA1_OFF + (wv * 64 + lane) * 8);
        acc = __builtin_amdgcn_mfma_f32_16x16x32_bf16(a, b, acc, 0, 0, 0);
#pragma unroll
        for (int r = 0; r < 4; ++r) pna[wv * 256 + (quad * 4 + r) * 16 + lm] = acc[r];
    }
    __syncthreads();
    int nn = tid >> 4, cc = tid & 15;
    {
        float t = na1_b[cc] + pna[nn * 16 + cc] + pna[256 + nn * 16 + cc]
                + pna[512 + nn * 16 + cc] + pna[768 + nn * 16 + cc];
        t1s[nn * 20 + cc] = fmaxf(t, 0.f);
    }
    __syncthreads();
    {
        float t2 = na2_b[cc];
#pragma unroll
        for (int k = 0; k < 16; ++k) t2 += t1s[nn * 20 + k] * na2_w[k * 16 + cc];
        int iN = i0 + nn;
        if (iN < n) a1[(size_t)iN * 16 + cc] = tob(fmaxf(t2, 0.f));
    }
}

// ---------------- agg2 fused: gather(hs2) -> x2; a2 MFMA; head f1/f2 MFMA, f3 -> sigmoid ----
// launch_bounds(256,6): cap VGPR at ~85 so the 8-deep gather can't trigger a hoist-everything
// allocation (spill or occupancy cliff); measured occupancy was ~21 waves/CU, cap is 24.

__global__ __launch_bounds__(256, 6) void agg2_kernel(
    const bf16* __restrict__ hs2, const int* __restrict__ offs, const int* __restrict__ pend,
    const int* __restrict__ csr,
    const float* __restrict__ dinv, const float* __restrict__ conv2_b,
    const unsigned short* __restrict__ wfrag,
    const float* __restrict__ na3_b,
    const float* __restrict__ na4_w, const float* __restrict__ na4_b,
    const bf16* __restrict__ gg, const bf16* __restrict__ a1,
    const float* __restrict__ f1_b, const float* __restrict__ f2_b,
    const float* __restrict__ f3_w, const float* __restrict__ f3_b,
    float* __restrict__ out, int n) {
    int tid = threadIdx.x;
    int g = tid >> 4, sl = tid & 15;
    int glane = tid & 48;
    int i0 = blockIdx.x * 16;
    int i = i0 + g;
    bool valid = (i < n);
    __shared__ short xsb[16 * 136];   // x2 bf16, stride 272 B
    __shared__ float pna[4 * 256];
    __shared__ float t1s[16 * 20];
    __shared__ short xf[16 * 72];     // concat [gg|a1|a2|0] bf16, stride 144 B
    __shared__ short y1[16 * 72];     // f1 out bf16, stride 144 B
    __shared__ float y2[16 * 36];     // f2 out f32
    GATHER16(hs2, STORE_X_BF16(conv2_b))
    __syncthreads();
    int lane = tid & 63, wv = tid >> 6, quad = lane >> 4, lm = lane & 15;
    // na3 via MFMA: wave wv K-step s=wv partial
    {
        f32x4 acc = {0.f, 0.f, 0.f, 0.f};
        short8 a = *(const short8*)((const char*)xsb + lm * 272 + wv * 64 + quad * 16);
        short8 b = *(const short8*)(wfrag + NA3_OFF + (wv * 64 + lane) * 8);
        acc = __builtin_amdgcn_mfma_f32_16x16x32_bf16(a, b, acc, 0, 0, 0);
#pragma unroll
        for (int r = 0; r < 4; ++r) pna[wv * 256 + (quad * 4 + r) * 16 + lm] = acc[r];
    }
    __syncthreads();
    int nn = tid >> 4, cc = tid & 15;
    int iN = i0 + nn;
    {
        float t = na3_b[cc] + pna[nn * 16 + cc] + pna[256 + nn * 16 + cc]
                + pna[512 + nn * 16 + cc] + pna[768 + nn * 16 + cc];
        t1s[nn * 20 + cc] = fmaxf(t, 0.f);
        bool v = (iN < n);
        size_t ib = (size_t)iN * 16 + cc;
        xf[nn * 72 + cc]      = v ? (short)((const unsigned short*)gg)[ib] : (short)0;
        xf[nn * 72 + 16 + cc] = v ? (short)((const unsigned short*)a1)[ib] : (short)0;
        xf[nn * 72 + 48 + cc] = 0;   // K-pad
    }
    __syncthreads();
    {
        float t2 = na4_b[cc];
#pragma unroll
        for (int k = 0; k < 16; ++k) t2 += t1s[nn * 20 + k] * na4_w[k * 16 + cc];
        xf[nn * 72 + 32 + cc] = (short)f2bf_bits(fmaxf(t2, 0.f));
    }
    __syncthreads();
    // f1 via MFMA: wave wv -> col-tile wv (64 cols / 4)
    {
        f32x4 acc = {0.f, 0.f, 0.f, 0.f};
#pragma unroll
        for (int s = 0; s < 2; ++s) {
            short8 a = *(const short8*)((const char*)xf + lm * 144 + s * 64 + quad * 16);
            short8 b = *(const short8*)(wfrag + F1_OFF + ((wv * 2 + s) * 64 + lane) * 8);
            acc = __builtin_amdgcn_mfma_f32_16x16x32_bf16(a, b, acc, 0, 0, 0);
        }
        float bia = f1_b[wv * 16 + lm];
#pragma unroll
        for (int r = 0; r < 4; ++r)
            y1[(quad * 4 + r) * 72 + wv * 16 + lm] = (short)f2bf_bits(fmaxf(acc[r] + bia, 0.f));
    }
    __syncthreads();
    // f2 via MFMA: waves 0,1 -> col-tiles 0,1 (32 cols)
    if (wv < 2) {
        f32x4 acc = {0.f, 0.f, 0.f, 0.f};
#pragma unroll
        for (int s = 0; s < 2; ++s) {
            short8 a = *(const short8*)((const char*)y1 + lm * 144 + s * 64 + quad * 16);
            short8 b = *(const short8*)(wfrag + F2_OFF + ((wv * 2 + s) * 64 + lane) * 8);
            acc = __builtin_amdgcn_mfma_f32_16x16x32_bf16(a, b, acc, 0, 0, 0);
        }
        float bia = f2_b[wv * 16 + lm];
#pragma unroll
        for (int r = 0; r < 4; ++r)
            y2[(quad * 4 + r) * 36 + wv * 16 + lm] = fmaxf(acc[r] + bia, 0.f);
    }
    __syncthreads();
    if (tid < 16) {
        float z = f3_b[0];
#pragma unroll
        for (int k = 0; k < 32; ++k) z += y2[tid * 36 + k] * f3_w[k];
        int io = i0 + tid;
        if (io < n) out[io] = 1.f / (1.f + expf(-z));
    }
}

// ---------------- launch (memset + 5 dispatches) ----------------

extern "C" void kernel_launch(void* const* d_in, const int* in_sizes, int n_in,
                              void* d_out, int out_size, void* d_ws, size_t ws_size,
                              hipStream_t stream) {
    const float* x       = (const float*)d_in[0];
    const int*   eidx    = (const int*)d_in[1];
    const float* conv1_w = (const float*)d_in[2];
    const float* conv1_b = (const float*)d_in[3];
    const float* conv2_w = (const float*)d_in[4];
    const float* conv2_b = (const float*)d_in[5];
    const float* ln1_w   = (const float*)d_in[6];
    const float* ln1_b   = (const float*)d_in[7];
    const float* ln2_w   = (const float*)d_in[8];
    const float* ln2_b   = (const float*)d_in[9];
    const float* na1_w   = (const float*)d_in[10];
    const float* na1_b   = (const float*)d_in[11];
    const float* na2_w   = (const float*)d_in[12];
    const float* na2_b   = (const float*)d_in[13];
    const float* na3_w   = (const float*)d_in[14];
    const float* na3_b   = (const float*)d_in[15];
    const float* na4_w   = (const float*)d_in[16];
    const float* na4_b   = (const float*)d_in[17];
    const float* f1_w    = (const float*)d_in[18];
    const float* f1_b    = (const float*)d_in[19];
    const float* f2_w    = (const float*)d_in[20];
    const float* f2_b    = (const float*)d_in[21];
    const float* f3_w    = (const float*)d_in[22];
    const float* f3_b    = (const float*)d_in[23];

    const int N = in_sizes[0] / 16;          // 50000 (< 65536: 16-bit packing valid)
    const int E = in_sizes[1] / 2;
    const int NBUCK = (N + 255) >> 8;
    const int EB = (E + CHUNK - 1) / CHUNK;
    const int NBLK = (N + 15) / 16;

    // workspace carve-up (256B aligned) — hsx (1.6 MB) aliases binned (binned dead by pre)
    char* p = (char*)d_ws;
    auto alloc = [&](size_t bytes) {
        char* r = p;
        p += (bytes + 255) & ~(size_t)255;
        return r;
    };
    size_t hs2_sz = ((size_t)N + 1) * 128 * 2;
    size_t hsx_sz = ((size_t)N + 1) * 16 * 2;
    size_t binned_sz = (size_t)NBUCK * REG * 4;
    size_t region_sz = (hsx_sz > binned_sz) ? hsx_sz : binned_sz;

    int*            bcur   = (int*)alloc(256 * 4);          // bucket-relative cursors (zeroed)
    int*            offs   = (int*)alloc((size_t)N * 4);
    int*            pend   = (int*)alloc((size_t)N * 4);
    float*          dinv   = (float*)alloc((size_t)N * 4);
    unsigned short* wfrag  = (unsigned short*)alloc((size_t)FRAG_TOT * 2);
    int*            csr    = (int*)alloc((size_t)NBUCK * PREG * 4 + 256);
    char*           region = (char*)alloc(region_sz);
    bf16*           hs2    = (bf16*)alloc(hs2_sz);
    bf16*           ggb    = (bf16*)alloc((size_t)N * 16 * 2);
    bf16*           a1b    = (bf16*)alloc((size_t)N * 16 * 2);

    unsigned* binned = (unsigned*)region;
    bf16*     hsx    = (bf16*)region;   // alias: binned dead before pre_kernel

    hipMemsetAsync(bcur, 0, 256 * 4, stream);

    prep_kernel<<<EB + FRAG_BLKS, 1024, 0, stream>>>(eidx, bcur, binned, E, EB,
                                                     conv2_w, na1_w, na3_w, f1_w, f2_w, wfrag);
    sort_kernel<<<NBUCK, 1024, 0, stream>>>(binned, bcur, offs, pend, dinv, csr, N, N);
    pre_kernel<<<NBLK, 256, 0, stream>>>(x, ln1_w, ln1_b, ln2_w, ln2_b, dinv, hsx, hs2, ggb, N);
    agg1_kernel<<<NBLK, 256, 0, stream>>>(hsx, offs, pend, csr, dinv, conv1_w, conv1_b, wfrag,
                                          na1_b, na2_w, na2_b, hs2, a1b, N);
    agg2_kernel<<<NBLK, 256, 0, stream>>>(hs2, offs, pend, csr, dinv, conv2_b, wfrag,
                                          na3_b, na4_w, na4_b, ggb, a1b,
                                          f1_b, f2_b, f3_w, f3_b, (float*)d_out, N);
}

// Round 8
// 214.346 us; speedup vs baseline: 1.3639x; 1.3639x over previous
//
#include <hip/hip_runtime.h>
#include <hip/hip_bf16.h>

typedef __hip_bfloat16 bf16;
typedef __attribute__((ext_vector_type(8))) short short8;
typedef __attribute__((ext_vector_type(4))) float f32x4;

__device__ __forceinline__ float tofb(bf16 v) { return __bfloat162float(v); }
__device__ __forceinline__ bf16 tob(float v) { return __float2bfloat16(v); }
// bf16x2 packed in a uint: low 16 bits = element 2m, high = element 2m+1
__device__ __forceinline__ float lo_f(unsigned v) { return __uint_as_float(v << 16); }
__device__ __forceinline__ float hi_f(unsigned v) { return __uint_as_float(v & 0xffff0000u); }
__device__ __forceinline__ unsigned f2bf_bits(float f) {  // RNE f32->bf16 bits
    unsigned u = __float_as_uint(f);
    return (u + 0x7fffu + ((u >> 16) & 1u)) >> 16;
}

#define CHUNK 4096   // edges per block in packbin
#define REG   9216   // fixed binned region per bucket (mean 8192, 11 sigma slack)
#define PREG  13312  // padded csr region per bucket (REG + 4096 pad slack, pad-16)

// fragment-buffer offsets (shorts): [t][s][lane][j] layout, 512 shorts per (t,s)
#define W2_OFF   0        // 128x128: t8 s4 -> 16384
#define NA1_OFF  16384    // 128x16:  t1 s4 -> 2048
#define NA3_OFF  18432    // 128x16:  t1 s4 -> 2048
#define F1_OFF   20480    // 48x64:   t4 s2 -> 4096 (k>=48 zero-padded)
#define F2_OFF   24576    // 64x32:   t2 s2 -> 2048
#define FRAG_TOT 26624
#define FRAG_BLKS ((FRAG_TOT + 1023) / 1024)

// ---------------- merged pass A (1024 threads/block): blocks [0,EB) packbin edges
//                  (LDS-staged counting sort -> coalesced binned writes, 4 edges/thread);
//                  blocks [EB,EB+FRAG_BLKS) pack dense weights to MFMA B-fragments.
//                  bcur pre-zeroed by hipMemsetAsync (bucket-relative cursors).
//                  NO per-edge global atomics (round-4 lesson: 1.6M device atomics = +35 us).
__global__ __launch_bounds__(1024) void prep_kernel(
    const int* __restrict__ eidx, int* __restrict__ bcur,
    unsigned* __restrict__ binned, int E, int EB,
    const float* __restrict__ w2, const float* __restrict__ na1w,
    const float* __restrict__ na3w, const float* __restrict__ f1w,
    const float* __restrict__ f2w, unsigned short* __restrict__ wf) {
    int t = threadIdx.x;
    if (blockIdx.x >= EB) {   // ---- pack_frags part ----
        int idx = (blockIdx.x - EB) * 1024 + t;
        const float* src;
        int Kdim, Ndim, S, rel, off;
        if (idx < 16384)      { src = w2;   Kdim = 128; Ndim = 128; S = 4; rel = idx;          off = W2_OFF; }
        else if (idx < 18432) { src = na1w; Kdim = 128; Ndim = 16;  S = 4; rel = idx - 16384;  off = NA1_OFF; }
        else if (idx < 20480) { src = na3w; Kdim = 128; Ndim = 16;  S = 4; rel = idx - 18432;  off = NA3_OFF; }
        else if (idx < 24576) { src = f1w;  Kdim = 48;  Ndim = 64;  S = 2; rel = idx - 20480;  off = F1_OFF; }
        else if (idx < FRAG_TOT) { src = f2w; Kdim = 64; Ndim = 32; S = 2; rel = idx - 24576;  off = F2_OFF; }
        else return;
        int j = rel & 7;
        int lane = (rel >> 3) & 63;
        int s = (rel >> 9) % S;
        int tt = rel / (512 * S);
        int k = s * 32 + ((lane >> 4) << 3) + j;
        int nn = tt * 16 + (lane & 15);
        unsigned short v = 0;
        if (k < Kdim) v = (unsigned short)f2bf_bits(src[k * Ndim + nn]);
        wf[off + rel] = v;
        return;
    }
    // ---- packbin part: LDS counting sort, then coalesced run writes ----
    __shared__ int h[256];
    __shared__ int lofs[256];
    __shared__ int lcur[256];
    __shared__ int gbase[256];
    __shared__ unsigned sorted[CHUNK];   // 16 KB
    __shared__ int sodd;
    if (t < 256) { h[t] = 0; lcur[t] = 0; }
    if (t == 0) sodd = 0;
    __syncthreads();
    if (t < 32) atomicOr(&sodd, eidx[2 * t + 1]);
    __syncthreads();
    int stride = (sodd == 0) ? 2 : 1;   // raw int64 => stride 2
    int base = blockIdx.x * CHUNK;
    int cnt = E - base; if (cnt > CHUNK) cnt = CHUNK;
    unsigned v[CHUNK / 1024];
#pragma unroll
    for (int k = 0; k < CHUNK / 1024; ++k) {
        int e = base + k * 1024 + t;
        if (e < E) {
            unsigned s = (unsigned)eidx[(size_t)e * stride];
            unsigned d = (unsigned)eidx[(size_t)E * stride + (size_t)e * stride];
            v[k] = (s << 16) | d;
            atomicAdd(&h[d >> 8], 1);
        } else {
            v[k] = 0xffffffffu;   // unused
        }
    }
    __syncthreads();
    int mycnt = (t < 256) ? h[t] : 0;
    if (t < 256) {
        if (mycnt) gbase[t] = t * REG + atomicAdd(&bcur[t], mycnt);  // bcur bucket-relative
        lofs[t] = mycnt;
    }
    __syncthreads();
    for (int off = 1; off < 256; off <<= 1) {            // inclusive scan of counts
        int x = (t >= off && t < 256) ? lofs[t - off] : 0;
        __syncthreads();
        if (t < 256) lofs[t] += x;
        __syncthreads();
    }
    int excl = (t < 256) ? (lofs[t] - mycnt) : 0;
    __syncthreads();
    if (t < 256) lofs[t] = excl;                         // exclusive offsets
    __syncthreads();
#pragma unroll
    for (int k = 0; k < CHUNK / 1024; ++k) {             // scatter into LDS (cheap atomics)
        int e = base + k * 1024 + t;
        if (e < E) {
            int b = (v[k] >> 8) & 255;
            int p = lofs[b] + atomicAdd(&lcur[b], 1);
            sorted[p] = v[k];
        }
    }
    __syncthreads();
    for (int j = t; j < cnt; j += 1024) {                // coalesced run writes to binned
        unsigned w = sorted[j];
        int b = (w >> 8) & 255;
        binned[gbase[b] + (j - lofs[b])] = w;
    }
}

// ---------------- pass B: per-bucket counting sort; FULL padded CSR image built in LDS,
//                  then one coalesced linear copy to global. 1024 threads/block. ----
__global__ __launch_bounds__(1024) void sort_kernel(const unsigned* __restrict__ binned,
                                                    const int* __restrict__ bcur,
                                                    int* __restrict__ offs,
                                                    int* __restrict__ pend,
                                                    float* __restrict__ dinv,
                                                    int* __restrict__ csr, int n, int zrow) {
    __shared__ int lcnt[256];
    __shared__ int lscan[256];
    __shared__ int lpos[256];
    __shared__ int sortedL[PREG];   // 53 KB padded CSR image
    int b = blockIdx.x, t = threadIdx.x;
    int bstart = b * REG;
    int bsize = bcur[b];            // bucket-relative count
    int pbase = b * PREG;
    if (t < 256) lcnt[t] = 0;
    __syncthreads();
    for (int e = t; e < bsize; e += 1024)
        atomicAdd(&lcnt[binned[bstart + e] & 255u], 1);
    __syncthreads();
    int node = (b << 8) + (t & 255);
    int myc = 0, mypad = 0;
    if (t < 256) {
        myc = lcnt[t];
        mypad = (node < n) ? ((myc + 1 + 15) & ~15) : 0;   // self + pad to multiple of 16
        lscan[t] = mypad;
    }
    __syncthreads();
    for (int off = 1; off < 256; off <<= 1) {
        int x = (t >= off && t < 256) ? lscan[t - off] : 0;
        __syncthreads();
        if (t < 256) lscan[t] += x;
        __syncthreads();
    }
    int totpad = lscan[255];
    if (t < 256) {
        int pexcl = lscan[t] - mypad;
        if (node < n) {
            offs[node] = pbase + pexcl;
            pend[node] = pbase + pexcl + mypad;
            dinv[node] = rsqrtf((float)myc + 1.0f);  // +1 self-loop
            sortedL[pexcl] = node;                   // self-loop entry
            for (int q = myc + 1; q < mypad; ++q) sortedL[pexcl + q] = zrow;
        }
        lpos[t] = pexcl + 1;                         // sources start after self
    }
    __syncthreads();
    for (int e = t; e < bsize; e += 1024) {
        unsigned v = binned[bstart + e];
        int p = atomicAdd(&lpos[v & 255u], 1);
        sortedL[p] = (int)(v >> 16);
    }
    __syncthreads();
    for (int j = t; j < totpad; j += 1024)           // fully coalesced CSR write
        csr[pbase + j] = sortedL[j];
}

// ---------------- pre-pass (16 nodes/block): hsx = dinv*x (bf16, 16-dim); gg; zero-rows ------
// Layer-1 commute: x1 = relu(dinv_i*(sum_j dinv_j x_j)@W1 + b1), so the gather table is the
// 16-dim dinv-scaled x (32 B/row, 1.6 MB total -> L2-resident) instead of 128-dim x@W1.

__global__ __launch_bounds__(256) void pre_kernel(
    const float* __restrict__ x,
    const float* __restrict__ ln1_w, const float* __restrict__ ln1_b,
    const float* __restrict__ ln2_w, const float* __restrict__ ln2_b,
    const float* __restrict__ dinv,
    bf16* __restrict__ hsx, bf16* __restrict__ hs2, bf16* __restrict__ gg, int n) {
    int tid = threadIdx.x;
    int i0 = blockIdx.x * 16;
    __shared__ float xls[16 * 20];   // [node][16] pad 20
    __shared__ float tg[16 * 36];    // ln1 out [node][32] pad 36
    if (blockIdx.x == 0) {           // zero rows (index n) for padded gathers
        if (tid < 16)  hsx[(size_t)n * 16 + tid] = tob(0.f);
        if (tid < 128) hs2[(size_t)n * 128 + tid] = tob(0.f);
    }
    {
        int nn = tid >> 4, cc = tid & 15;
        int i = i0 + nn;
        float xv = (i < n) ? x[(size_t)i * 16 + cc] : 0.f;
        xls[nn * 20 + cc] = xv;
        if (i < n) hsx[(size_t)i * 16 + cc] = tob(dinv[i] * xv);
    }
    __syncthreads();
    {
        int c = tid & 31, q = tid >> 5;
        float t0 = ln1_b[c], t1 = t0;
#pragma unroll
        for (int k = 0; k < 16; ++k) {
            float w = ln1_w[k * 32 + c];
            t0 += xls[q * 20 + k] * w;
            t1 += xls[(q + 8) * 20 + k] * w;
        }
        tg[q * 36 + c] = fmaxf(t0, 0.f);
        tg[(q + 8) * 36 + c] = fmaxf(t1, 0.f);
    }
    __syncthreads();
    {
        int nn = tid >> 4, cc = tid & 15;
        float t = ln2_b[cc];
#pragma unroll 8
        for (int k = 0; k < 32; ++k) t += tg[nn * 36 + k] * ln2_w[k * 16 + cc];
        int i = i0 + nn;
        if (i < n) gg[(size_t)i * 16 + cc] = tob(fmaxf(t, 0.f));
    }
}

#define ACC8(v)                              \
    a0 += lo_f((v).x); a1 += hi_f((v).x);    \
    a2 += lo_f((v).y); a3 += hi_f((v).y);    \
    a4 += lo_f((v).z); a5 += hi_f((v).z);    \
    a6 += lo_f((v).w); a7 += hi_f((v).w);

#define RED8(m)                                                  \
    a0 += __shfl_xor(a0, m); a1 += __shfl_xor(a1, m);            \
    a2 += __shfl_xor(a2, m); a3 += __shfl_xor(a3, m);            \
    a4 += __shfl_xor(a4, m); a5 += __shfl_xor(a5, m);            \
    a6 += __shfl_xor(a6, m); a7 += __shfl_xor(a7, m);

// R15-proven gather loop: rolled 4-deep pipeline (no spill), padded branchless CSR,
// + next-chunk CSR prefetch (idxn issues before the accumulate, consumed next iter;
//   reading 64 B past pend is safe: csr has PREG slack + 256 B tail).
// Round-7 lesson: deeper hand-pipelining (8/16 in flight) makes the scheduler hoist all
// loads -> scratch spill (WRITE_SIZE 0.2->217 MB, 2.7x slower). VGPR=32 rolled-4 is the
// compiler's stable fixed point; agg2 is at the L2-miss service floor of this algorithm.
// group g (16 lanes) owns node i; lane sl covers cols sl*8..+7.
#define GATHER16(hs, ...)                                                            \
    {                                                                                \
        const char* base = (const char*)(hs);                                        \
        int off16 = sl * 16;                                                         \
        float a0 = 0.f, a1 = 0.f, a2 = 0.f, a3 = 0.f,                                \
              a4 = 0.f, a5 = 0.f, a6 = 0.f, a7 = 0.f;                                \
        int e0 = 0, e1 = 0;                                                          \
        if (valid) { e0 = offs[i]; e1 = pend[i]; }                                   \
        int idxv = (e0 < e1) ? csr[e0 + sl] : 0;                                     \
        for (int cb = e0; cb < e1; cb += 16) {                                       \
            int idxn = csr[cb + 16 + sl];                                            \
            _Pragma("unroll 2")                                                      \
            for (int u = 0; u < 4; ++u) {                                            \
                int s0 = __shfl(idxv, glane + u * 4 + 0);                            \
                int s1 = __shfl(idxv, glane + u * 4 + 1);                            \
                int s2 = __shfl(idxv, glane + u * 4 + 2);                            \
                int s3 = __shfl(idxv, glane + u * 4 + 3);                            \
                uint4 v0 = *(const uint4*)(base + (size_t)s0 * 256 + off16);         \
                uint4 v1 = *(const uint4*)(base + (size_t)s1 * 256 + off16);         \
                uint4 v2 = *(const uint4*)(base + (size_t)s2 * 256 + off16);         \
                uint4 v3 = *(const uint4*)(base + (size_t)s3 * 256 + off16);         \
                ACC8(v0) ACC8(v1) ACC8(v2) ACC8(v3)                                  \
            }                                                                        \
            idxv = idxn;                                                             \
        }                                                                            \
        __VA_ARGS__                                                                  \
    }

// epilogue: relu(dinv*acc + bias) -> bf16 row in LDS xsb (stride 272 B)
#define STORE_X_BF16(biasptr)                                                        \
    {                                                                                \
        float r0 = 0.f; float r1 = 0.f; float r2 = 0.f; float r3 = 0.f;              \
        float r4 = 0.f; float r5 = 0.f; float r6 = 0.f; float r7 = 0.f;              \
        if (valid) {                                                                 \
            float di = dinv[i];                                                      \
            const float* b = (biasptr) + sl * 8;                                     \
            r0 = fmaxf(di * a0 + b[0], 0.f); r1 = fmaxf(di * a1 + b[1], 0.f);        \
            r2 = fmaxf(di * a2 + b[2], 0.f); r3 = fmaxf(di * a3 + b[3], 0.f);        \
            r4 = fmaxf(di * a4 + b[4], 0.f); r5 = fmaxf(di * a5 + b[5], 0.f);        \
            r6 = fmaxf(di * a6 + b[6], 0.f); r7 = fmaxf(di * a7 + b[7], 0.f);        \
        }                                                                            \
        uint4 pk;                                                                    \
        pk.x = f2bf_bits(r0) | (f2bf_bits(r1) << 16);                                \
        pk.y = f2bf_bits(r2) | (f2bf_bits(r3) << 16);                                \
        pk.z = f2bf_bits(r4) | (f2bf_bits(r5) << 16);                                \
        pk.w = f2bf_bits(r6) | (f2bf_bits(r7) << 16);                                \
        *(uint4*)((char*)xsb + g * 272 + sl * 16) = pk;                              \
    }

// ---------------- agg1 fused: gather 16-dim hsx -> aggx; x1 = relu(aggx@W1+b1) (VALU);
//                  hs2=dinv*(x1@W2) MFMA; a1 branch MFMA ----

__global__ __launch_bounds__(256) void agg1_kernel(
    const bf16* __restrict__ hsx, const int* __restrict__ offs, const int* __restrict__ pend,
    const int* __restrict__ csr,
    const float* __restrict__ dinv,
    const float* __restrict__ conv1_w, const float* __restrict__ conv1_b,
    const unsigned short* __restrict__ wfrag,
    const float* __restrict__ na1_b,
    const float* __restrict__ na2_w, const float* __restrict__ na2_b,
    bf16* __restrict__ hs2, bf16* __restrict__ a1, int n) {
    int tid = threadIdx.x;
    int g = tid >> 4, sl = tid & 15;
    int glane = tid & 48;
    int i0 = blockIdx.x * 16;
    int i = i0 + g;
    bool valid = (i < n);
    __shared__ float aggx[16 * 20];   // aggregated dinv-scaled x, [node][16] f32 pad 20
    __shared__ short xsb[16 * 136];   // x1 bf16, row stride 272 B
    __shared__ float pna[4 * 256];    // na1 per-wave partials
    __shared__ float t1s[16 * 20];
    // gather: 32-B rows, 2 lanes per row (col-halves), 16 rows per CSR chunk, csr prefetch
    {
        const char* base = (const char*)hsx;
        int off16 = (sl & 1) * 16;
        int rsel = glane + (sl >> 1);
        float a0 = 0.f, a1 = 0.f, a2 = 0.f, a3 = 0.f,
              a4 = 0.f, a5 = 0.f, a6 = 0.f, a7 = 0.f;   // local a1 shadows param (scope-limited)
        int e0 = 0, e1 = 0;
        if (valid) { e0 = offs[i]; e1 = pend[i]; }
        int idxv = (e0 < e1) ? csr[e0 + sl] : 0;
        for (int cb = e0; cb < e1; cb += 16) {
            int idxn = csr[cb + 16 + sl];   // safe: PREG slack + tail
            int s0 = __shfl(idxv, rsel);
            int s1 = __shfl(idxv, rsel + 8);
            uint4 v0 = *(const uint4*)(base + (size_t)s0 * 32 + off16);
            uint4 v1 = *(const uint4*)(base + (size_t)s1 * 32 + off16);
            ACC8(v0) ACC8(v1)
            idxv = idxn;
        }
        RED8(2) RED8(4) RED8(8)
        if (sl < 2) {
            float di = valid ? dinv[i] : 0.f;
            float4 p0 = {di * a0, di * a1, di * a2, di * a3};
            float4 p1 = {di * a4, di * a5, di * a6, di * a7};
            *(float4*)(aggx + g * 20 + sl * 8) = p0;
            *(float4*)(aggx + g * 20 + sl * 8 + 4) = p1;
        }
    }
    __syncthreads();
    // x1 = relu(aggx @ W1 + b1) -> bf16 rows in xsb (VALU, 16x128x16 per block)
    {
        int c = tid & 127, half = tid >> 7;
        float h[8];
#pragma unroll
        for (int r = 0; r < 8; ++r) h[r] = 0.f;
#pragma unroll
        for (int k = 0; k < 16; ++k) {
            float w = conv1_w[k * 128 + c];
#pragma unroll
            for (int r = 0; r < 8; ++r) h[r] += aggx[(half + 2 * r) * 20 + k] * w;
        }
        float bia = conv1_b[c];
#pragma unroll
        for (int r = 0; r < 8; ++r) {
            int nd = half + 2 * r;
            float v = fmaxf(h[r] + bia, 0.f);
            if (i0 + nd >= n) v = 0.f;
            xsb[nd * 136 + c] = (short)f2bf_bits(v);
        }
    }
    __syncthreads();
    int lane = tid & 63, wv = tid >> 6, quad = lane >> 4, lm = lane & 15;
    // conv2 via MFMA: wave wv covers col-tiles 2wv, 2wv+1
    {
        int t0 = wv * 2;
        f32x4 acc0 = {0.f, 0.f, 0.f, 0.f};
        f32x4 acc1 = {0.f, 0.f, 0.f, 0.f};
#pragma unroll
        for (int s = 0; s < 4; ++s) {
            short8 a = *(const short8*)((const char*)xsb + lm * 272 + s * 64 + quad * 16);
            short8 b0 = *(const short8*)(wfrag + W2_OFF + ((t0 * 4 + s) * 64 + lane) * 8);
            short8 b1 = *(const short8*)(wfrag + W2_OFF + (((t0 + 1) * 4 + s) * 64 + lane) * 8);
            acc0 = __builtin_amdgcn_mfma_f32_16x16x32_bf16(a, b0, acc0, 0, 0, 0);
            acc1 = __builtin_amdgcn_mfma_f32_16x16x32_bf16(a, b1, acc1, 0, 0, 0);
        }
#pragma unroll
        for (int r = 0; r < 4; ++r) {
            int iN = i0 + quad * 4 + r;
            if (iN < n) {
                float di = dinv[iN];
                hs2[(size_t)iN * 128 + t0 * 16 + lm] = tob(di * acc0[r]);
                hs2[(size_t)iN * 128 + (t0 + 1) * 16 + lm] = tob(di * acc1[r]);
            }
        }
    }
    // na1 via MFMA: wave wv computes K-step s=wv partial
    {
        f32x4 acc = {0.f, 0.f, 0.f, 0.f};
        short8 a = *(const short8*)((const char*)xsb + lm * 272 + wv * 64 + quad * 16);
        short8 b = *(const short8*)(wfrag + NA1_OFF + (wv * 64 + lane) * 8);
        acc = __builtin_amdgcn_mfma_f32_16x16x32_bf16(a, b, acc, 0, 0, 0);
#pragma unroll
        for (int r = 0; r < 4; ++r) pna[wv * 256 + (quad * 4 + r) * 16 + lm] = acc[r];
    }
    __syncthreads();
    int nn = tid >> 4, cc = tid & 15;
    {
        float t = na1_b[cc] + pna[nn * 16 + cc] + pna[256 + nn * 16 + cc]
                + pna[512 + nn * 16 + cc] + pna[768 + nn * 16 + cc];
        t1s[nn * 20 + cc] = fmaxf(t, 0.f);
    }
    __syncthreads();
    {
        float t2 = na2_b[cc];
#pragma unroll
        for (int k = 0; k < 16; ++k) t2 += t1s[nn * 20 + k] * na2_w[k * 16 + cc];
        int iN = i0 + nn;
        if (iN < n) a1[(size_t)iN * 16 + cc] = tob(fmaxf(t2, 0.f));
    }
}

// ---------------- agg2 fused: gather(hs2) -> x2; a2 MFMA; head f1/f2 MFMA, f3 -> sigmoid ----

__global__ __launch_bounds__(256) void agg2_kernel(
    const bf16* __restrict__ hs2, const int* __restrict__ offs, const int* __restrict__ pend,
    const int* __restrict__ csr,
    const float* __restrict__ dinv, const float* __restrict__ conv2_b,
    const unsigned short* __restrict__ wfrag,
    const float* __restrict__ na3_b,
    const float* __restrict__ na4_w, const float* __restrict__ na4_b,
    const bf16* __restrict__ gg, const bf16* __restrict__ a1,
    const float* __restrict__ f1_b, const float* __restrict__ f2_b,
    const float* __restrict__ f3_w, const float* __restrict__ f3_b,
    float* __restrict__ out, int n) {
    int tid = threadIdx.x;
    int g = tid >> 4, sl = tid & 15;
    int glane = tid & 48;
    int i0 = blockIdx.x * 16;
    int i = i0 + g;
    bool valid = (i < n);
    __shared__ short xsb[16 * 136];   // x2 bf16, stride 272 B
    __shared__ float pna[4 * 256];
    __shared__ float t1s[16 * 20];
    __shared__ short xf[16 * 72];     // concat [gg|a1|a2|0] bf16, stride 144 B
    __shared__ short y1[16 * 72];     // f1 out bf16, stride 144 B
    __shared__ float y2[16 * 36];     // f2 out f32
    GATHER16(hs2, STORE_X_BF16(conv2_b))
    __syncthreads();
    int lane = tid & 63, wv = tid >> 6, quad = lane >> 4, lm = lane & 15;
    // na3 via MFMA: wave wv K-step s=wv partial
    {
        f32x4 acc = {0.f, 0.f, 0.f, 0.f};
        short8 a = *(const short8*)((const char*)xsb + lm * 272 + wv * 64 + quad * 16);
        short8 b = *(const short8*)(wfrag + NA3_OFF + (wv * 64 + lane) * 8);
        acc = __builtin_amdgcn_mfma_f32_16x16x32_bf16(a, b, acc, 0, 0, 0);
#pragma unroll
        for (int r = 0; r < 4; ++r) pna[wv * 256 + (quad * 4 + r) * 16 + lm] = acc[r];
    }
    __syncthreads();
    int nn = tid >> 4, cc = tid & 15;
    int iN = i0 + nn;
    {
        float t = na3_b[cc] + pna[nn * 16 + cc] + pna[256 + nn * 16 + cc]
                + pna[512 + nn * 16 + cc] + pna[768 + nn * 16 + cc];
        t1s[nn * 20 + cc] = fmaxf(t, 0.f);
        bool v = (iN < n);
        size_t ib = (size_t)iN * 16 + cc;
        xf[nn * 72 + cc]      = v ? (short)((const unsigned short*)gg)[ib] : (short)0;
        xf[nn * 72 + 16 + cc] = v ? (short)((const unsigned short*)a1)[ib] : (short)0;
        xf[nn * 72 + 48 + cc] = 0;   // K-pad
    }
    __syncthreads();
    {
        float t2 = na4_b[cc];
#pragma unroll
        for (int k = 0; k < 16; ++k) t2 += t1s[nn * 20 + k] * na4_w[k * 16 + cc];
        xf[nn * 72 + 32 + cc] = (short)f2bf_bits(fmaxf(t2, 0.f));
    }
    __syncthreads();
    // f1 via MFMA: wave wv -> col-tile wv (64 cols / 4)
    {
        f32x4 acc = {0.f, 0.f, 0.f, 0.f};
#pragma unroll
        for (int s = 0; s < 2; ++s) {
            short8 a = *(const short8*)((const char*)xf + lm * 144 + s * 64 + quad * 16);
            short8 b = *(const short8*)(wfrag + F1_OFF + ((wv * 2 + s) * 64 + lane) * 8);
            acc = __builtin_amdgcn_mfma_f32_16x16x32_bf16(a, b, acc, 0, 0, 0);
        }
        float bia = f1_b[wv * 16 + lm];
#pragma unroll
        for (int r = 0; r < 4; ++r)
            y1[(quad * 4 + r) * 72 + wv * 16 + lm] = (short)f2bf_bits(fmaxf(acc[r] + bia, 0.f));
    }
    __syncthreads();
    // f2 via MFMA: waves 0,1 -> col-tiles 0,1 (32 cols)
    if (wv < 2) {
        f32x4 acc = {0.f, 0.f, 0.f, 0.f};
#pragma unroll
        for (int s = 0; s < 2; ++s) {
            short8 a = *(const short8*)((const char*)y1 + lm * 144 + s * 64 + quad * 16);
            short8 b = *(const short8*)(wfrag + F2_OFF + ((wv * 2 + s) * 64 + lane) * 8);
            acc = __builtin_amdgcn_mfma_f32_16x16x32_bf16(a, b, acc, 0, 0, 0);
        }
        float bia = f2_b[wv * 16 + lm];
#pragma unroll
        for (int r = 0; r < 4; ++r)
            y2[(quad * 4 + r) * 36 + wv * 16 + lm] = fmaxf(acc[r] + bia, 0.f);
    }
    __syncthreads();
    if (tid < 16) {
        float z = f3_b[0];
#pragma unroll
        for (int k = 0; k < 32; ++k) z += y2[tid * 36 + k] * f3_w[k];
        int io = i0 + tid;
        if (io < n) out[io] = 1.f / (1.f + expf(-z));
    }
}

// ---------------- launch (memset + 5 dispatches) ----------------

extern "C" void kernel_launch(void* const* d_in, const int* in_sizes, int n_in,
                              void* d_out, int out_size, void* d_ws, size_t ws_size,
                              hipStream_t stream) {
    const float* x       = (const float*)d_in[0];
    const int*   eidx    = (const int*)d_in[1];
    const float* conv1_w = (const float*)d_in[2];
    const float* conv1_b = (const float*)d_in[3];
    const float* conv2_w = (const float*)d_in[4];
    const float* conv2_b = (const float*)d_in[5];
    const float* ln1_w   = (const float*)d_in[6];
    const float* ln1_b   = (const float*)d_in[7];
    const float* ln2_w   = (const float*)d_in[8];
    const float* ln2_b   = (const float*)d_in[9];
    const float* na1_w   = (const float*)d_in[10];
    const float* na1_b   = (const float*)d_in[11];
    const float* na2_w   = (const float*)d_in[12];
    const float* na2_b   = (const float*)d_in[13];
    const float* na3_w   = (const float*)d_in[14];
    const float* na3_b   = (const float*)d_in[15];
    const float* na4_w   = (const float*)d_in[16];
    const float* na4_b   = (const float*)d_in[17];
    const float* f1_w    = (const float*)d_in[18];
    const float* f1_b    = (const float*)d_in[19];
    const float* f2_w    = (const float*)d_in[20];
    const float* f2_b    = (const float*)d_in[21];
    const float* f3_w    = (const float*)d_in[22];
    const float* f3_b    = (const float*)d_in[23];

    const int N = in_sizes[0] / 16;          // 50000 (< 65536: 16-bit packing valid)
    const int E = in_sizes[1] / 2;
    const int NBUCK = (N + 255) >> 8;
    const int EB = (E + CHUNK - 1) / CHUNK;
    const int NBLK = (N + 15) / 16;

    // workspace carve-up (256B aligned) — hsx (1.6 MB) aliases binned (binned dead by pre)
    char* p = (char*)d_ws;
    auto alloc = [&](size_t bytes) {
        char* r = p;
        p += (bytes + 255) & ~(size_t)255;
        return r;
    };
    size_t hs2_sz = ((size_t)N + 1) * 128 * 2;
    size_t hsx_sz = ((size_t)N + 1) * 16 * 2;
    size_t binned_sz = (size_t)NBUCK * REG * 4;
    size_t region_sz = (hsx_sz > binned_sz) ? hsx_sz : binned_sz;

    int*            bcur   = (int*)alloc(256 * 4);          // bucket-relative cursors (zeroed)
    int*            offs   = (int*)alloc((size_t)N * 4);
    int*            pend   = (int*)alloc((size_t)N * 4);
    float*          dinv   = (float*)alloc((size_t)N * 4);
    unsigned short* wfrag  = (unsigned short*)alloc((size_t)FRAG_TOT * 2);
    int*            csr    = (int*)alloc((size_t)NBUCK * PREG * 4 + 256);
    char*           region = (char*)alloc(region_sz);
    bf16*           hs2    = (bf16*)alloc(hs2_sz);
    bf16*           ggb    = (bf16*)alloc((size_t)N * 16 * 2);
    bf16*           a1b    = (bf16*)alloc((size_t)N * 16 * 2);

    unsigned* binned = (unsigned*)region;
    bf16*     hsx    = (bf16*)region;   // alias: binned dead before pre_kernel

    hipMemsetAsync(bcur, 0, 256 * 4, stream);

    prep_kernel<<<EB + FRAG_BLKS, 1024, 0, stream>>>(eidx, bcur, binned, E, EB,
                                                     conv2_w, na1_w, na3_w, f1_w, f2_w, wfrag);
    sort_kernel<<<NBUCK, 1024, 0, stream>>>(binned, bcur, offs, pend, dinv, csr, N, N);
    pre_kernel<<<NBLK, 256, 0, stream>>>(x, ln1_w, ln1_b, ln2_w, ln2_b, dinv, hsx, hs2, ggb, N);
    agg1_kernel<<<NBLK, 256, 0, stream>>>(hsx, offs, pend, csr, dinv, conv1_w, conv1_b, wfrag,
                                          na1_b, na2_w, na2_b, hs2, a1b, N);
    agg2_kernel<<<NBLK, 256, 0, stream>>>(hs2, offs, pend, csr, dinv, conv2_b, wfrag,
                                          na3_b, na4_w, na4_b, ggb, a1b,
                                          f1_b, f2_b, f3_w, f3_b, (float*)d_out, N);
}